// Round 1
// baseline (1252.253 us; speedup 1.0000x reference)
//
#include <hip/hip_runtime.h>
#include <hip/hip_bf16.h>

#define LR 0.01f

typedef __attribute__((ext_vector_type(8))) short short8;
typedef __attribute__((ext_vector_type(4))) float float4v;
typedef __attribute__((ext_vector_type(4))) unsigned short ushort4v;

static __device__ __forceinline__ unsigned short f2bf(float x) {
    union { float f; unsigned u; } un; un.f = x;
    unsigned r = un.u + 0x7fffu + ((un.u >> 16) & 1u);   // RNE
    return (unsigned short)(r >> 16);
}
static __device__ __forceinline__ float bf2f(unsigned short x) {
    union { float f; unsigned u; } un; un.u = ((unsigned)x) << 16;
    return un.f;
}

// ---------------------------------------------------------------------------
// Phase 1: K/V/Q projections, bf16 out. Also writes Kt = -LR * K^T  [b][j][s].
// ---------------------------------------------------------------------------
__global__ __launch_bounds__(256) void proj_gemm(
    const float* __restrict__ A,
    const float* __restrict__ T0, const float* __restrict__ T1,
    const float* __restrict__ T2,
    unsigned short* __restrict__ out,
    unsigned short* __restrict__ ktw)
{
    const float* Bt = (blockIdx.z == 0) ? T0 : (blockIdx.z == 1 ? T1 : T2);
    unsigned short* C = out + (size_t)blockIdx.z * (size_t)16384 * 1024;

    __shared__ unsigned short As[64][40];
    __shared__ unsigned short Bs[64][40];

    const int tid  = threadIdx.x;
    const int lane = tid & 63;
    const int wave = tid >> 6;
    const int m0 = blockIdx.x * 64;
    const int n0 = blockIdx.y * 64;
    const int srow = tid >> 2;
    const int sseg = (tid & 3) * 8;
    const int mrow = lane & 15;
    const int quad = lane >> 4;

    float4v acc[4];
#pragma unroll
    for (int i = 0; i < 4; ++i) acc[i] = (float4v){0.f, 0.f, 0.f, 0.f};

    const float* apBase = A  + (size_t)(m0 + srow) * 1024 + sseg;
    const float* bpBase = Bt + (size_t)(n0 + srow) * 1024 + sseg;

    for (int kt = 0; kt < 1024; kt += 32) {
        const float4v* ap4 = (const float4v*)(apBase + kt);
        const float4v* bp4 = (const float4v*)(bpBase + kt);
        float4v av0 = ap4[0], av1 = ap4[1];
        float4v bv0 = bp4[0], bv1 = bp4[1];

        __syncthreads();
        short8 apk, bpk;
#pragma unroll
        for (int i = 0; i < 4; ++i) {
            apk[i]     = (short)f2bf(av0[i]);
            apk[i + 4] = (short)f2bf(av1[i]);
            bpk[i]     = (short)f2bf(bv0[i]);
            bpk[i + 4] = (short)f2bf(bv1[i]);
        }
        *(short8*)&As[srow][sseg] = apk;
        *(short8*)&Bs[srow][sseg] = bpk;
        __syncthreads();

        short8 af = *(const short8*)&As[16 * wave + mrow][quad * 8];
#pragma unroll
        for (int nb = 0; nb < 4; ++nb) {
            short8 bfr = *(const short8*)&Bs[16 * nb + mrow][quad * 8];
            acc[nb] = __builtin_amdgcn_mfma_f32_16x16x32_bf16(af, bfr, acc[nb], 0, 0, 0);
        }
    }

    const int batch = m0 >> 11;
    const int s0    = m0 & 2047;
#pragma unroll
    for (int nb = 0; nb < 4; ++nb) {
#pragma unroll
        for (int r = 0; r < 4; ++r) {
            int tl = 16 * wave + quad * 4 + r;     // token-local
            int jl = 16 * nb + mrow;               // dim-local
            C[(size_t)(m0 + tl) * 1024 + (n0 + jl)] = f2bf(acc[nb][r]);
            if (blockIdx.z == 0) {
                ktw[(size_t)batch * 2097152 + (size_t)(n0 + jl) * 2048 + s0 + tl] =
                    f2bf(-LR * acc[nb][r]);
            }
        }
    }
}

// ---------------------------------------------------------------------------
// Phase 2: per (batch, chunk): Linv = (I+L)^-1 via Neumann (I - L + L^2 - L^3),
// Mp = -LR * tril(Q K^T + 1). L = (2LR/d)*strict_tril(K K^T + 1).
// ---------------------------------------------------------------------------
__global__ __launch_bounds__(256) void precomp(
    const unsigned short* __restrict__ K,
    const unsigned short* __restrict__ Q,
    unsigned short* __restrict__ LinvG,
    unsigned short* __restrict__ MpG)
{
    __shared__ float Skk[64][68];
    __shared__ float Sqk[64][68];
    __shared__ unsigned short Lb[64][72];
    __shared__ unsigned short Xa[64][72];

    const int tid = threadIdx.x;
    const int lane = tid & 63;
    const int w = tid >> 6;
    const int lm = lane & 15;
    const int quad = lane >> 4;
    const int batch = blockIdx.x >> 5;
    const int c = blockIdx.x & 31;
    const size_t blk = (size_t)batch * 32 + c;

    float4v kk[4], qk[4];
#pragma unroll
    for (int i = 0; i < 4; ++i) { kk[i] = (float4v){0,0,0,0}; qk[i] = (float4v){0,0,0,0}; }

    const size_t tokA = (size_t)batch * 2048 + c * 64 + w * 16 + lm;
#pragma unroll 4
    for (int ks = 0; ks < 32; ++ks) {
        short8 aK = *(const short8*)(K + tokA * 1024 + ks * 32 + quad * 8);
        short8 aQ = *(const short8*)(Q + tokA * 1024 + ks * 32 + quad * 8);
#pragma unroll
        for (int nb = 0; nb < 4; ++nb) {
            size_t tokB = (size_t)batch * 2048 + c * 64 + nb * 16 + lm;
            short8 bK = *(const short8*)(K + tokB * 1024 + ks * 32 + quad * 8);
            kk[nb] = __builtin_amdgcn_mfma_f32_16x16x32_bf16(aK, bK, kk[nb], 0, 0, 0);
            qk[nb] = __builtin_amdgcn_mfma_f32_16x16x32_bf16(aQ, bK, qk[nb], 0, 0, 0);
        }
    }
#pragma unroll
    for (int nb = 0; nb < 4; ++nb)
#pragma unroll
        for (int r = 0; r < 4; ++r) {
            Skk[w * 16 + quad * 4 + r][nb * 16 + lm] = kk[nb][r];
            Sqk[w * 16 + quad * 4 + r][nb * 16 + lm] = qk[nb][r];
        }
    __syncthreads();

    const float c1 = 2.0f * LR / 1024.0f;
#pragma unroll
    for (int e = 0; e < 16; ++e) {
        int idx = tid * 16 + e;
        int t = idx >> 6, i = idx & 63;
        float a = (i < t) ? c1 * (Skk[t][i] + 1.0f) : 0.0f;
        Lb[t][i] = f2bf(a);
        Xa[i][t] = f2bf(((i == t) ? 1.0f : 0.0f) - a);
        float mq = (i <= t) ? -LR * (Sqk[t][i] + 1.0f) : 0.0f;
        MpG[blk * 4096 + (size_t)t * 64 + i] = f2bf(mq);
    }
    __syncthreads();

    short8 afL0 = *(const short8*)&Lb[w * 16 + lm][quad * 8];
    short8 afL1 = *(const short8*)&Lb[w * 16 + lm][32 + quad * 8];
    float4v p[4];
#pragma unroll
    for (int nb = 0; nb < 4; ++nb) {
        p[nb] = (float4v){0,0,0,0};
        short8 b0f = *(const short8*)&Xa[nb * 16 + lm][quad * 8];
        short8 b1f = *(const short8*)&Xa[nb * 16 + lm][32 + quad * 8];
        p[nb] = __builtin_amdgcn_mfma_f32_16x16x32_bf16(afL0, b0f, p[nb], 0, 0, 0);
        p[nb] = __builtin_amdgcn_mfma_f32_16x16x32_bf16(afL1, b1f, p[nb], 0, 0, 0);
    }
    __syncthreads();
#pragma unroll
    for (int nb = 0; nb < 4; ++nb)
#pragma unroll
        for (int r = 0; r < 4; ++r) {
            int ii = nb * 16 + lm, tt = w * 16 + quad * 4 + r;
            Xa[ii][tt] = f2bf(((ii == tt) ? 1.0f : 0.0f) - p[nb][r]);
        }
    __syncthreads();

#pragma unroll
    for (int nb = 0; nb < 4; ++nb) {
        p[nb] = (float4v){0,0,0,0};
        short8 b0f = *(const short8*)&Xa[nb * 16 + lm][quad * 8];
        short8 b1f = *(const short8*)&Xa[nb * 16 + lm][32 + quad * 8];
        p[nb] = __builtin_amdgcn_mfma_f32_16x16x32_bf16(afL0, b0f, p[nb], 0, 0, 0);
        p[nb] = __builtin_amdgcn_mfma_f32_16x16x32_bf16(afL1, b1f, p[nb], 0, 0, 0);
    }
#pragma unroll
    for (int nb = 0; nb < 4; ++nb)
#pragma unroll
        for (int r = 0; r < 4; ++r) {
            int ii = nb * 16 + lm, tt = w * 16 + quad * 4 + r;
            LinvG[blk * 4096 + (size_t)tt * 64 + ii] =
                f2bf(((ii == tt) ? 1.0f : 0.0f) - p[nb][r]);
        }
}

// ---------------------------------------------------------------------------
// Phase 3: chunked TTT. 512 blocks = 8 batches x 64 row-slabs (16 rows each),
// now 512 threads (8 waves) per block: wave = (token-group g = w&3, k-half
// kh = w>>2). Step (b) contraction is k-split across kh and reduced through
// fp32 LDS (RU/RO); kh=0 waves own U->G, kh=1 waves own O->store. W-update
// tiles split 8 ways (nt = w + 8i). Fragment roles identical to the verified
// 4-wave kernel (w -> g substitution only).
//   16 waves/CU (2 blocks/CU) vs previous 8: double latency hiding.
// ---------------------------------------------------------------------------
__global__ __launch_bounds__(512, 4) void ttt_chunk(
    const unsigned short* __restrict__ K,
    const unsigned short* __restrict__ V,
    const unsigned short* __restrict__ Q,
    const unsigned short* __restrict__ Kt,
    const unsigned short* __restrict__ Linv,
    const unsigned short* __restrict__ Mp,
    const float* __restrict__ W0,
    const float* __restrict__ b0,
    float* __restrict__ out)
{
    __shared__ unsigned short Wb[16][1032];   // bf16 W mirror (33 KB)
    __shared__ float RU[2][16][68];           // U partials per k-half (8.7 KB)
    __shared__ float RO[2][16][68];           // O partials per k-half (8.7 KB)
    __shared__ unsigned short Ut[16][72];
    __shared__ unsigned short Gt[16][72];
    __shared__ __align__(16) float bb[16];

    const int tid  = threadIdx.x;
    const int lane = tid & 63;
    const int w    = tid >> 6;          // wave 0..7
    const int g    = w & 3;             // token-group
    const int kh   = w >> 2;            // k-half
    const int lm   = lane & 15;
    const int quad = lane >> 4;
    const int batch = blockIdx.x & 7;
    const int r0    = (blockIdx.x >> 3) * 16;   // row-slab base

    // W init: wave w owns col-tiles nt = w + 8i (i<8); rows quad*4+r.
    float4v acc_w[8];
#pragma unroll
    for (int i = 0; i < 8; ++i) {
        int nt = w + 8 * i;
#pragma unroll
        for (int r = 0; r < 4; ++r)
            acc_w[i][r] = W0[(size_t)(r0 + quad * 4 + r) * 1024 + nt * 16 + lm];
    }
    if (tid < 16) bb[tid] = b0[r0 + tid];

    const size_t tokBase = (size_t)batch * 2048;
    const unsigned short* KtB = Kt + (size_t)batch * 2097152;
    const float sc = 2.0f / 1024.0f;

    for (int c = 0; c < 32; ++c) {
        // (a) dump fp32 W regs -> bf16 LDS mirror
#pragma unroll
        for (int i = 0; i < 8; ++i) {
            int nt = w + 8 * i;
#pragma unroll
            for (int r = 0; r < 4; ++r)
                Wb[quad * 4 + r][nt * 16 + lm] = f2bf(acc_w[i][r]);
        }
        __syncthreads();   // B1: Wb ready

        // (b) k-split: accU/accO partials over this wave's 512-dim half
        const size_t tok = tokBase + c * 64 + g * 16 + lm;   // this lane's token
        float4v accU = (float4v){0,0,0,0};
        float4v accO = (float4v){0,0,0,0};
        const int ks0 = kh * 16;
#pragma unroll 8
        for (int ks = ks0; ks < ks0 + 16; ++ks) {
            short8 af = *(const short8*)&Wb[lm][ks * 32 + quad * 8];
            short8 kf = *(const short8*)(K + tok * 1024 + ks * 32 + quad * 8);
            short8 qf = *(const short8*)(Q + tok * 1024 + ks * 32 + quad * 8);
            accU = __builtin_amdgcn_mfma_f32_16x16x32_bf16(af, kf, accU, 0, 0, 0);
            accO = __builtin_amdgcn_mfma_f32_16x16x32_bf16(af, qf, accO, 0, 0, 0);
        }
#pragma unroll
        for (int r = 0; r < 4; ++r) {
            RU[kh][quad * 4 + r][g * 16 + lm] = accU[r];
            RO[kh][quad * 4 + r][g * 16 + lm] = accO[r];
        }
        __syncthreads();   // B2: partials ready

        // combine: kh=0 builds U (bf16 Ut); kh=1 builds full O in regs
        float4v bval = *(const float4v*)&bb[quad * 4];
        if (kh == 0) {
            ushort4v vv = *(const ushort4v*)(V + tok * 1024 + r0 + quad * 4);
#pragma unroll
            for (int r = 0; r < 4; ++r) {
                float sum = RU[0][quad * 4 + r][g * 16 + lm]
                          + RU[1][quad * 4 + r][g * 16 + lm];
                float uval = sc * (sum + bval[r] - bf2f(vv[r]));
                Ut[quad * 4 + r][g * 16 + lm] = f2bf(uval);
            }
        } else {
#pragma unroll
            for (int r = 0; r < 4; ++r)
                accO[r] = RO[0][quad * 4 + r][g * 16 + lm]
                        + RO[1][quad * 4 + r][g * 16 + lm];
        }
        __syncthreads();   // B3: Ut ready

        const size_t lbase = ((size_t)(batch * 32 + c)) * 4096 + (size_t)(g * 16 + lm) * 64;

        // (c) G^T = Ut . Linv^T-contraction (kh=0 waves)
        if (kh == 0) {
            float4v accG = (float4v){0,0,0,0};
            short8 a0 = *(const short8*)&Ut[lm][quad * 8];
            short8 a1 = *(const short8*)&Ut[lm][32 + quad * 8];
            short8 l0 = *(const short8*)(Linv + lbase + quad * 8);
            short8 l1 = *(const short8*)(Linv + lbase + 32 + quad * 8);
            accG = __builtin_amdgcn_mfma_f32_16x16x32_bf16(a0, l0, accG, 0, 0, 0);
            accG = __builtin_amdgcn_mfma_f32_16x16x32_bf16(a1, l1, accG, 0, 0, 0);
#pragma unroll
            for (int r = 0; r < 4; ++r)
                Gt[quad * 4 + r][g * 16 + lm] = f2bf(accG[r]);
        }
        __syncthreads();   // B4: Gt ready

        short8 ag0 = *(const short8*)&Gt[lm][quad * 8];
        short8 ag1 = *(const short8*)&Gt[lm][32 + quad * 8];

        // (d) O += Gt . Mp-contraction + b ; store (kh=1 waves)
        if (kh == 1) {
            short8 m0f = *(const short8*)(Mp + lbase + quad * 8);
            short8 m1f = *(const short8*)(Mp + lbase + 32 + quad * 8);
            accO = __builtin_amdgcn_mfma_f32_16x16x32_bf16(ag0, m0f, accO, 0, 0, 0);
            accO = __builtin_amdgcn_mfma_f32_16x16x32_bf16(ag1, m1f, accO, 0, 0, 0);
            float4v ov;
#pragma unroll
            for (int r = 0; r < 4; ++r) ov[r] = accO[r] + bval[r];
            *(float4v*)(out + tok * 1024 + r0 + quad * 4) = ov;
        }

        // (e) W += Gt . Kt-contraction (all waves, 8 tiles each)
#pragma unroll
        for (int i = 0; i < 8; ++i) {
            int nt = w + 8 * i;
            const unsigned short* kp = KtB + (size_t)(nt * 16 + lm) * 2048 + c * 64;
            short8 kb0 = *(const short8*)(kp + quad * 8);
            short8 kb1 = *(const short8*)(kp + 32 + quad * 8);
            acc_w[i] = __builtin_amdgcn_mfma_f32_16x16x32_bf16(ag0, kb0, acc_w[i], 0, 0, 0);
            acc_w[i] = __builtin_amdgcn_mfma_f32_16x16x32_bf16(ag1, kb1, acc_w[i], 0, 0, 0);
        }

        // (f) bias update: wave 0, 4 lanes per row + shuffle reduce
        if (w == 0) {
            int row = lane >> 2, part = lane & 3;
            float s = 0.f;
#pragma unroll
            for (int t = 0; t < 16; ++t) s += bf2f(Gt[row][part * 16 + t]);
            s += __shfl_xor(s, 1);
            s += __shfl_xor(s, 2);
            if (part == 0) bb[row] -= LR * s;
        }
        __syncthreads();   // B5: bb/Gt/RU safe for next chunk
    }
}

// ---------------------------------------------------------------------------
extern "C" void kernel_launch(void* const* d_in, const int* in_sizes, int n_in,
                              void* d_out, int out_size, void* d_ws, size_t ws_size,
                              hipStream_t stream) {
    (void)in_sizes; (void)n_in; (void)out_size; (void)ws_size;
    const float* in_seq = (const float*)d_in[0];
    const float* thK    = (const float*)d_in[1];
    const float* thV    = (const float*)d_in[2];
    const float* thQ    = (const float*)d_in[3];
    const float* W0     = (const float*)d_in[4];
    const float* b0     = (const float*)d_in[5];
    float* out = (float*)d_out;

    unsigned short* ws = (unsigned short*)d_ws;
    unsigned short* Kp   = ws;                                  // 32 MB
    unsigned short* Vp   = ws + (size_t)16384 * 1024;           // 32 MB
    unsigned short* Qp   = ws + (size_t)2 * 16384 * 1024;       // 32 MB
    unsigned short* Ktp  = ws + (size_t)3 * 16384 * 1024;       // 32 MB
    unsigned short* Linv = ws + (size_t)4 * 16384 * 1024;       // 2 MB
    unsigned short* Mpp  = Linv + (size_t)8 * 32 * 4096;        // 2 MB

    dim3 g1(16384 / 64, 1024 / 64, 3);
    proj_gemm<<<g1, 256, 0, stream>>>(in_seq, thK, thV, thQ, Kp, Ktp);

    precomp<<<256, 256, 0, stream>>>(Kp, Qp, Linv, Mpp);

    ttt_chunk<<<512, 512, 0, stream>>>(Kp, Vp, Qp, Ktp, Linv, Mpp, W0, b0, out);
}

// Round 3
// 1037.690 us; speedup vs baseline: 1.2068x; 1.2068x over previous
//
#include <hip/hip_runtime.h>
#include <hip/hip_bf16.h>

#define LR 0.01f

typedef __attribute__((ext_vector_type(8))) short short8;
typedef __attribute__((ext_vector_type(4))) float float4v;
typedef __attribute__((ext_vector_type(4))) unsigned short ushort4v;

static __device__ __forceinline__ unsigned short f2bf(float x) {
    union { float f; unsigned u; } un; un.f = x;
    unsigned r = un.u + 0x7fffu + ((un.u >> 16) & 1u);   // RNE
    return (unsigned short)(r >> 16);
}
static __device__ __forceinline__ float bf2f(unsigned short x) {
    union { float f; unsigned u; } un; un.u = ((unsigned)x) << 16;
    return un.f;
}

// ---------------------------------------------------------------------------
// Phase 1: K/V/Q projections, bf16 out, z-merged: one block stages an A-tile
// once and contracts it against all three theta tiles (A fp32 re-read 3 GB->1 GB).
// Also writes Kt = -LR * K^T  [b][j][s].
// ---------------------------------------------------------------------------
__global__ __launch_bounds__(256) void proj_gemm(
    const float* __restrict__ A,
    const float* __restrict__ T0, const float* __restrict__ T1,
    const float* __restrict__ T2,
    unsigned short* __restrict__ out,
    unsigned short* __restrict__ ktw)
{
    __shared__ unsigned short As[64][40];
    __shared__ unsigned short Bs[3][64][40];

    const int tid  = threadIdx.x;
    const int lane = tid & 63;
    const int wave = tid >> 6;
    const int m0 = blockIdx.x * 64;
    const int n0 = blockIdx.y * 64;
    const int srow = tid >> 2;
    const int sseg = (tid & 3) * 8;
    const int mrow = lane & 15;
    const int quad = lane >> 4;

    float4v acc[3][4];
#pragma unroll
    for (int z = 0; z < 3; ++z)
#pragma unroll
        for (int i = 0; i < 4; ++i) acc[z][i] = (float4v){0.f, 0.f, 0.f, 0.f};

    const float* apBase = A  + (size_t)(m0 + srow) * 1024 + sseg;
    const float* bp0 = T0 + (size_t)(n0 + srow) * 1024 + sseg;
    const float* bp1 = T1 + (size_t)(n0 + srow) * 1024 + sseg;
    const float* bp2 = T2 + (size_t)(n0 + srow) * 1024 + sseg;

    for (int kt = 0; kt < 1024; kt += 32) {
        float4v av0 = ((const float4v*)(apBase + kt))[0];
        float4v av1 = ((const float4v*)(apBase + kt))[1];
        float4v b00 = ((const float4v*)(bp0 + kt))[0], b01 = ((const float4v*)(bp0 + kt))[1];
        float4v b10 = ((const float4v*)(bp1 + kt))[0], b11 = ((const float4v*)(bp1 + kt))[1];
        float4v b20 = ((const float4v*)(bp2 + kt))[0], b21 = ((const float4v*)(bp2 + kt))[1];

        __syncthreads();
        short8 apk, bpk0, bpk1, bpk2;
#pragma unroll
        for (int i = 0; i < 4; ++i) {
            apk[i]      = (short)f2bf(av0[i]);
            apk[i + 4]  = (short)f2bf(av1[i]);
            bpk0[i]     = (short)f2bf(b00[i]);
            bpk0[i + 4] = (short)f2bf(b01[i]);
            bpk1[i]     = (short)f2bf(b10[i]);
            bpk1[i + 4] = (short)f2bf(b11[i]);
            bpk2[i]     = (short)f2bf(b20[i]);
            bpk2[i + 4] = (short)f2bf(b21[i]);
        }
        *(short8*)&As[srow][sseg]    = apk;
        *(short8*)&Bs[0][srow][sseg] = bpk0;
        *(short8*)&Bs[1][srow][sseg] = bpk1;
        *(short8*)&Bs[2][srow][sseg] = bpk2;
        __syncthreads();

        short8 af = *(const short8*)&As[16 * wave + mrow][quad * 8];
#pragma unroll
        for (int z = 0; z < 3; ++z)
#pragma unroll
            for (int nb = 0; nb < 4; ++nb) {
                short8 bfr = *(const short8*)&Bs[z][16 * nb + mrow][quad * 8];
                acc[z][nb] = __builtin_amdgcn_mfma_f32_16x16x32_bf16(af, bfr, acc[z][nb], 0, 0, 0);
            }
    }

    const int batch = m0 >> 11;
    const int s0    = m0 & 2047;
#pragma unroll
    for (int z = 0; z < 3; ++z) {
        unsigned short* C = out + (size_t)z * (size_t)16384 * 1024;
#pragma unroll
        for (int nb = 0; nb < 4; ++nb) {
#pragma unroll
            for (int r = 0; r < 4; ++r) {
                int tl = 16 * wave + quad * 4 + r;     // token-local
                int jl = 16 * nb + mrow;               // dim-local
                C[(size_t)(m0 + tl) * 1024 + (n0 + jl)] = f2bf(acc[z][nb][r]);
                if (z == 0) {
                    ktw[(size_t)batch * 2097152 + (size_t)(n0 + jl) * 2048 + s0 + tl] =
                        f2bf(-LR * acc[0][nb][r]);
                }
            }
        }
    }
}

// ---------------------------------------------------------------------------
// Phase 2: per (batch, chunk): Linv = (I+L)^-1 via Neumann (I - L + L^2 - L^3),
// Mp = -LR * tril(Q K^T + 1). L = (2LR/d)*strict_tril(K K^T + 1).  (unchanged)
// ---------------------------------------------------------------------------
__global__ __launch_bounds__(256) void precomp(
    const unsigned short* __restrict__ K,
    const unsigned short* __restrict__ Q,
    unsigned short* __restrict__ LinvG,
    unsigned short* __restrict__ MpG)
{
    __shared__ float Skk[64][68];
    __shared__ float Sqk[64][68];
    __shared__ unsigned short Lb[64][72];
    __shared__ unsigned short Xa[64][72];

    const int tid = threadIdx.x;
    const int lane = tid & 63;
    const int w = tid >> 6;
    const int lm = lane & 15;
    const int quad = lane >> 4;
    const int batch = blockIdx.x >> 5;
    const int c = blockIdx.x & 31;
    const size_t blk = (size_t)batch * 32 + c;

    float4v kk[4], qk[4];
#pragma unroll
    for (int i = 0; i < 4; ++i) { kk[i] = (float4v){0,0,0,0}; qk[i] = (float4v){0,0,0,0}; }

    const size_t tokA = (size_t)batch * 2048 + c * 64 + w * 16 + lm;
#pragma unroll 4
    for (int ks = 0; ks < 32; ++ks) {
        short8 aK = *(const short8*)(K + tokA * 1024 + ks * 32 + quad * 8);
        short8 aQ = *(const short8*)(Q + tokA * 1024 + ks * 32 + quad * 8);
#pragma unroll
        for (int nb = 0; nb < 4; ++nb) {
            size_t tokB = (size_t)batch * 2048 + c * 64 + nb * 16 + lm;
            short8 bK = *(const short8*)(K + tokB * 1024 + ks * 32 + quad * 8);
            kk[nb] = __builtin_amdgcn_mfma_f32_16x16x32_bf16(aK, bK, kk[nb], 0, 0, 0);
            qk[nb] = __builtin_amdgcn_mfma_f32_16x16x32_bf16(aQ, bK, qk[nb], 0, 0, 0);
        }
    }
#pragma unroll
    for (int nb = 0; nb < 4; ++nb)
#pragma unroll
        for (int r = 0; r < 4; ++r) {
            Skk[w * 16 + quad * 4 + r][nb * 16 + lm] = kk[nb][r];
            Sqk[w * 16 + quad * 4 + r][nb * 16 + lm] = qk[nb][r];
        }
    __syncthreads();

    const float c1 = 2.0f * LR / 1024.0f;
#pragma unroll
    for (int e = 0; e < 16; ++e) {
        int idx = tid * 16 + e;
        int t = idx >> 6, i = idx & 63;
        float a = (i < t) ? c1 * (Skk[t][i] + 1.0f) : 0.0f;
        Lb[t][i] = f2bf(a);
        Xa[i][t] = f2bf(((i == t) ? 1.0f : 0.0f) - a);
        float mq = (i <= t) ? -LR * (Sqk[t][i] + 1.0f) : 0.0f;
        MpG[blk * 4096 + (size_t)t * 64 + i] = f2bf(mq);
    }
    __syncthreads();

    short8 afL0 = *(const short8*)&Lb[w * 16 + lm][quad * 8];
    short8 afL1 = *(const short8*)&Lb[w * 16 + lm][32 + quad * 8];
    float4v p[4];
#pragma unroll
    for (int nb = 0; nb < 4; ++nb) {
        p[nb] = (float4v){0,0,0,0};
        short8 b0f = *(const short8*)&Xa[nb * 16 + lm][quad * 8];
        short8 b1f = *(const short8*)&Xa[nb * 16 + lm][32 + quad * 8];
        p[nb] = __builtin_amdgcn_mfma_f32_16x16x32_bf16(afL0, b0f, p[nb], 0, 0, 0);
        p[nb] = __builtin_amdgcn_mfma_f32_16x16x32_bf16(afL1, b1f, p[nb], 0, 0, 0);
    }
    __syncthreads();
#pragma unroll
    for (int nb = 0; nb < 4; ++nb)
#pragma unroll
        for (int r = 0; r < 4; ++r) {
            int ii = nb * 16 + lm, tt = w * 16 + quad * 4 + r;
            Xa[ii][tt] = f2bf(((ii == tt) ? 1.0f : 0.0f) - p[nb][r]);
        }
    __syncthreads();

#pragma unroll
    for (int nb = 0; nb < 4; ++nb) {
        p[nb] = (float4v){0,0,0,0};
        short8 b0f = *(const short8*)&Xa[nb * 16 + lm][quad * 8];
        short8 b1f = *(const short8*)&Xa[nb * 16 + lm][32 + quad * 8];
        p[nb] = __builtin_amdgcn_mfma_f32_16x16x32_bf16(afL0, b0f, p[nb], 0, 0, 0);
        p[nb] = __builtin_amdgcn_mfma_f32_16x16x32_bf16(afL1, b1f, p[nb], 0, 0, 0);
    }
#pragma unroll
    for (int nb = 0; nb < 4; ++nb)
#pragma unroll
        for (int r = 0; r < 4; ++r) {
            int ii = nb * 16 + lm, tt = w * 16 + quad * 4 + r;
            LinvG[blk * 4096 + (size_t)tt * 64 + ii] =
                f2bf(((ii == tt) ? 1.0f : 0.0f) - p[nb][r]);
        }
}

// ---------------------------------------------------------------------------
// Phase 3: chunked TTT. 256 blocks = 8 batches x 32 row-slabs (32 rows each),
// 512 threads (8 waves): wave = (token-group g = w&3, row-slab rs = w>>2).
// Halves total K/Q/Kt cache traffic vs the 16-row version (the measured
// bottleneck: ~6.3 GB served at ~8 TB/s aggregate = L3 roofline).
// 4 barriers/chunk, no fp32 partial-reduce buffers.
// Fragment roles identical to the verified kernel modulo rs-offset.
//   acc_w[rs2][i][r] = W[row = r0 + rs2*16 + quad*4 + r][col = (w+8i)*16 + lm]
// ---------------------------------------------------------------------------
__global__ __launch_bounds__(512, 2) void ttt_chunk(
    const unsigned short* __restrict__ K,
    const unsigned short* __restrict__ V,
    const unsigned short* __restrict__ Q,
    const unsigned short* __restrict__ Kt,
    const unsigned short* __restrict__ Linv,
    const unsigned short* __restrict__ Mp,
    const float* __restrict__ W0,
    const float* __restrict__ b0,
    float* __restrict__ out)
{
    __shared__ unsigned short Wb[32][1032];   // bf16 W mirror (66 KB)
    __shared__ unsigned short Ut[32][72];
    __shared__ unsigned short Gt[32][72];
    __shared__ __align__(16) float bb[32];

    const int tid  = threadIdx.x;
    const int lane = tid & 63;
    const int w    = tid >> 6;          // wave 0..7
    const int g    = w & 3;             // token-group
    const int rs   = w >> 2;            // row-slab half (this wave's U/G/O rows)
    const int lm   = lane & 15;
    const int quad = lane >> 4;
    const int batch = blockIdx.x & 7;
    const int r0    = (blockIdx.x >> 3) * 32;   // row-slab base (32 rows)

    // W init: wave w owns col-tiles nt = w + 8i (i<8), BOTH row halves.
    float4v acc_w[2][8];
#pragma unroll
    for (int rs2 = 0; rs2 < 2; ++rs2)
#pragma unroll
        for (int i = 0; i < 8; ++i) {
            int nt = w + 8 * i;
#pragma unroll
            for (int r = 0; r < 4; ++r)
                acc_w[rs2][i][r] =
                    W0[(size_t)(r0 + rs2 * 16 + quad * 4 + r) * 1024 + nt * 16 + lm];
        }
    if (tid < 32) bb[tid] = b0[r0 + tid];

    const size_t tokBase = (size_t)batch * 2048;
    const unsigned short* KtB = Kt + (size_t)batch * 2097152;
    const float sc = 2.0f / 1024.0f;

    for (int c = 0; c < 32; ++c) {
        // (a) dump fp32 W regs -> bf16 LDS mirror (both halves)
#pragma unroll
        for (int rs2 = 0; rs2 < 2; ++rs2)
#pragma unroll
            for (int i = 0; i < 8; ++i) {
                int nt = w + 8 * i;
#pragma unroll
                for (int r = 0; r < 4; ++r)
                    Wb[rs2 * 16 + quad * 4 + r][nt * 16 + lm] = f2bf(acc_w[rs2][i][r]);
            }
        __syncthreads();   // B1: Wb ready

        // (b) U = (2/d)(W K^T + b - V) and O_acc = W Q^T, full-k, own (g,rs) tile
        const size_t tok = tokBase + c * 64 + g * 16 + lm;   // this lane's token
        const unsigned short* kRow = K + tok * 1024 + quad * 8;
        const unsigned short* qRow = Q + tok * 1024 + quad * 8;
        const unsigned short* wRow = &Wb[rs * 16 + lm][quad * 8];
        float4v accU = (float4v){0,0,0,0};
        float4v accO = (float4v){0,0,0,0};
#pragma unroll 8
        for (int ks = 0; ks < 32; ++ks) {
            short8 af = *(const short8*)(wRow + ks * 32);
            short8 kf = *(const short8*)(kRow + ks * 32);
            short8 qf = *(const short8*)(qRow + ks * 32);
            accU = __builtin_amdgcn_mfma_f32_16x16x32_bf16(af, kf, accU, 0, 0, 0);
            accO = __builtin_amdgcn_mfma_f32_16x16x32_bf16(af, qf, accO, 0, 0, 0);
        }
        float4v bval = *(const float4v*)&bb[rs * 16 + quad * 4];
        ushort4v vv = *(const ushort4v*)(V + tok * 1024 + r0 + rs * 16 + quad * 4);
#pragma unroll
        for (int r = 0; r < 4; ++r) {
            float uval = sc * (accU[r] + bval[r] - bf2f(vv[r]));
            Ut[rs * 16 + quad * 4 + r][g * 16 + lm] = f2bf(uval);
        }
        __syncthreads();   // B2: Ut ready

        const size_t lbase = ((size_t)(batch * 32 + c)) * 4096 + (size_t)(g * 16 + lm) * 64;

        // (c) G^T = Ut . Linv^T-contraction (own (g,rs) tile)
        {
            float4v accG = (float4v){0,0,0,0};
            short8 a0 = *(const short8*)&Ut[rs * 16 + lm][quad * 8];
            short8 a1 = *(const short8*)&Ut[rs * 16 + lm][32 + quad * 8];
            short8 l0 = *(const short8*)(Linv + lbase + quad * 8);
            short8 l1 = *(const short8*)(Linv + lbase + 32 + quad * 8);
            accG = __builtin_amdgcn_mfma_f32_16x16x32_bf16(a0, l0, accG, 0, 0, 0);
            accG = __builtin_amdgcn_mfma_f32_16x16x32_bf16(a1, l1, accG, 0, 0, 0);
#pragma unroll
            for (int r = 0; r < 4; ++r)
                Gt[rs * 16 + quad * 4 + r][g * 16 + lm] = f2bf(accG[r]);
        }
        __syncthreads();   // B3: Gt ready

        // (d) O += Gt . Mp-contraction + b ; store (own (g,rs) tile)
        {
            short8 agO0 = *(const short8*)&Gt[rs * 16 + lm][quad * 8];
            short8 agO1 = *(const short8*)&Gt[rs * 16 + lm][32 + quad * 8];
            short8 m0f = *(const short8*)(Mp + lbase + quad * 8);
            short8 m1f = *(const short8*)(Mp + lbase + 32 + quad * 8);
            accO = __builtin_amdgcn_mfma_f32_16x16x32_bf16(agO0, m0f, accO, 0, 0, 0);
            accO = __builtin_amdgcn_mfma_f32_16x16x32_bf16(agO1, m1f, accO, 0, 0, 0);
            float4v ov;
#pragma unroll
            for (int r = 0; r < 4; ++r) ov[r] = accO[r] + bval[r];
            *(float4v*)(out + tok * 1024 + r0 + rs * 16 + quad * 4) = ov;
        }

        // (e) W += Gt . Kt-contraction, both halves share each Kt load
        short8 agA0 = *(const short8*)&Gt[lm][quad * 8];
        short8 agA1 = *(const short8*)&Gt[lm][32 + quad * 8];
        short8 agB0 = *(const short8*)&Gt[16 + lm][quad * 8];
        short8 agB1 = *(const short8*)&Gt[16 + lm][32 + quad * 8];
#pragma unroll
        for (int i = 0; i < 8; ++i) {
            int nt = w + 8 * i;
            const unsigned short* kp = KtB + (size_t)(nt * 16 + lm) * 2048 + c * 64;
            short8 kb0 = *(const short8*)(kp + quad * 8);
            short8 kb1 = *(const short8*)(kp + 32 + quad * 8);
            acc_w[0][i] = __builtin_amdgcn_mfma_f32_16x16x32_bf16(agA0, kb0, acc_w[0][i], 0, 0, 0);
            acc_w[0][i] = __builtin_amdgcn_mfma_f32_16x16x32_bf16(agA1, kb1, acc_w[0][i], 0, 0, 0);
            acc_w[1][i] = __builtin_amdgcn_mfma_f32_16x16x32_bf16(agB0, kb0, acc_w[1][i], 0, 0, 0);
            acc_w[1][i] = __builtin_amdgcn_mfma_f32_16x16x32_bf16(agB1, kb1, acc_w[1][i], 0, 0, 0);
        }

        // (f) bias update: wave 0, 2 lanes per row + shuffle reduce (32 rows)
        if (w == 0) {
            int row = lane >> 1, part = lane & 1;
            float s = 0.f;
#pragma unroll
            for (int t = 0; t < 32; ++t) s += bf2f(Gt[row][part * 32 + t]);
            s += __shfl_xor(s, 1);
            if (part == 0) bb[row] -= LR * s;
        }
        __syncthreads();   // B4: bb/Gt/Wb safe for next chunk
    }
}

// ---------------------------------------------------------------------------
extern "C" void kernel_launch(void* const* d_in, const int* in_sizes, int n_in,
                              void* d_out, int out_size, void* d_ws, size_t ws_size,
                              hipStream_t stream) {
    (void)in_sizes; (void)n_in; (void)out_size; (void)ws_size;
    const float* in_seq = (const float*)d_in[0];
    const float* thK    = (const float*)d_in[1];
    const float* thV    = (const float*)d_in[2];
    const float* thQ    = (const float*)d_in[3];
    const float* W0     = (const float*)d_in[4];
    const float* b0     = (const float*)d_in[5];
    float* out = (float*)d_out;

    unsigned short* ws = (unsigned short*)d_ws;
    unsigned short* Kp   = ws;                                  // 32 MB
    unsigned short* Vp   = ws + (size_t)16384 * 1024;           // 32 MB
    unsigned short* Qp   = ws + (size_t)2 * 16384 * 1024;       // 32 MB
    unsigned short* Ktp  = ws + (size_t)3 * 16384 * 1024;       // 32 MB
    unsigned short* Linv = ws + (size_t)4 * 16384 * 1024;       // 2 MB
    unsigned short* Mpp  = Linv + (size_t)8 * 32 * 4096;        // 2 MB

    dim3 g1(16384 / 64, 1024 / 64);
    proj_gemm<<<g1, 256, 0, stream>>>(in_seq, thK, thV, thQ, Kp, Ktp);

    precomp<<<256, 256, 0, stream>>>(Kp, Qp, Linv, Mpp);

    ttt_chunk<<<256, 512, 0, stream>>>(Kp, Vp, Qp, Ktp, Linv, Mpp, W0, b0, out);
}

// Round 7
// 819.713 us; speedup vs baseline: 1.5277x; 1.2659x over previous
//
#include <hip/hip_runtime.h>
#include <hip/hip_bf16.h>

#define LR 0.01f

typedef __attribute__((ext_vector_type(8))) short short8;
typedef __attribute__((ext_vector_type(4))) float float4v;
typedef __attribute__((ext_vector_type(4))) unsigned short ushort4v;

static __device__ __forceinline__ unsigned short f2bf(float x) {
    union { float f; unsigned u; } un; un.f = x;
    unsigned r = un.u + 0x7fffu + ((un.u >> 16) & 1u);   // RNE
    return (unsigned short)(r >> 16);
}
static __device__ __forceinline__ float bf2f(unsigned short x) {
    union { float f; unsigned u; } un; un.u = ((unsigned)x) << 16;
    return un.f;
}

// ---------------------------------------------------------------------------
// Phase 1: K/V/Q projections, bf16 out, z-merged (verified round 3).
// Also writes Kt = -LR * K^T  [b][j][s].
// ---------------------------------------------------------------------------
__global__ __launch_bounds__(256) void proj_gemm(
    const float* __restrict__ A,
    const float* __restrict__ T0, const float* __restrict__ T1,
    const float* __restrict__ T2,
    unsigned short* __restrict__ out,
    unsigned short* __restrict__ ktw)
{
    __shared__ unsigned short As[64][40];
    __shared__ unsigned short Bs[3][64][40];

    const int tid  = threadIdx.x;
    const int lane = tid & 63;
    const int wave = tid >> 6;
    const int m0 = blockIdx.x * 64;
    const int n0 = blockIdx.y * 64;
    const int srow = tid >> 2;
    const int sseg = (tid & 3) * 8;
    const int mrow = lane & 15;
    const int quad = lane >> 4;

    float4v acc[3][4];
#pragma unroll
    for (int z = 0; z < 3; ++z)
#pragma unroll
        for (int i = 0; i < 4; ++i) acc[z][i] = (float4v){0.f, 0.f, 0.f, 0.f};

    const float* apBase = A  + (size_t)(m0 + srow) * 1024 + sseg;
    const float* bp0 = T0 + (size_t)(n0 + srow) * 1024 + sseg;
    const float* bp1 = T1 + (size_t)(n0 + srow) * 1024 + sseg;
    const float* bp2 = T2 + (size_t)(n0 + srow) * 1024 + sseg;

    for (int kt = 0; kt < 1024; kt += 32) {
        float4v av0 = ((const float4v*)(apBase + kt))[0];
        float4v av1 = ((const float4v*)(apBase + kt))[1];
        float4v b00 = ((const float4v*)(bp0 + kt))[0], b01 = ((const float4v*)(bp0 + kt))[1];
        float4v b10 = ((const float4v*)(bp1 + kt))[0], b11 = ((const float4v*)(bp1 + kt))[1];
        float4v b20 = ((const float4v*)(bp2 + kt))[0], b21 = ((const float4v*)(bp2 + kt))[1];

        __syncthreads();
        short8 apk, bpk0, bpk1, bpk2;
#pragma unroll
        for (int i = 0; i < 4; ++i) {
            apk[i]      = (short)f2bf(av0[i]);
            apk[i + 4]  = (short)f2bf(av1[i]);
            bpk0[i]     = (short)f2bf(b00[i]);
            bpk0[i + 4] = (short)f2bf(b01[i]);
            bpk1[i]     = (short)f2bf(b10[i]);
            bpk1[i + 4] = (short)f2bf(b11[i]);
            bpk2[i]     = (short)f2bf(b20[i]);
            bpk2[i + 4] = (short)f2bf(b21[i]);
        }
        *(short8*)&As[srow][sseg]    = apk;
        *(short8*)&Bs[0][srow][sseg] = bpk0;
        *(short8*)&Bs[1][srow][sseg] = bpk1;
        *(short8*)&Bs[2][srow][sseg] = bpk2;
        __syncthreads();

        short8 af = *(const short8*)&As[16 * wave + mrow][quad * 8];
#pragma unroll
        for (int z = 0; z < 3; ++z)
#pragma unroll
            for (int nb = 0; nb < 4; ++nb) {
                short8 bfr = *(const short8*)&Bs[z][16 * nb + mrow][quad * 8];
                acc[z][nb] = __builtin_amdgcn_mfma_f32_16x16x32_bf16(af, bfr, acc[z][nb], 0, 0, 0);
            }
    }

    const int batch = m0 >> 11;
    const int s0    = m0 & 2047;
#pragma unroll
    for (int z = 0; z < 3; ++z) {
        unsigned short* C = out + (size_t)z * (size_t)16384 * 1024;
#pragma unroll
        for (int nb = 0; nb < 4; ++nb) {
#pragma unroll
            for (int r = 0; r < 4; ++r) {
                int tl = 16 * wave + quad * 4 + r;     // token-local
                int jl = 16 * nb + mrow;               // dim-local
                C[(size_t)(m0 + tl) * 1024 + (n0 + jl)] = f2bf(acc[z][nb][r]);
                if (z == 0) {
                    ktw[(size_t)batch * 2097152 + (size_t)(n0 + jl) * 2048 + s0 + tl] =
                        f2bf(-LR * acc[0][nb][r]);
                }
            }
        }
    }
}

// ---------------------------------------------------------------------------
// Phase 2: per (batch, chunk): Linv = (I+L)^-1 via Neumann (I - L + L^2 - L^3),
// Mp = -LR * tril(Q K^T + 1). L = (2LR/d)*strict_tril(K K^T + 1).  (unchanged)
// ---------------------------------------------------------------------------
__global__ __launch_bounds__(256) void precomp(
    const unsigned short* __restrict__ K,
    const unsigned short* __restrict__ Q,
    unsigned short* __restrict__ LinvG,
    unsigned short* __restrict__ MpG)
{
    __shared__ float Skk[64][68];
    __shared__ float Sqk[64][68];
    __shared__ unsigned short Lb[64][72];
    __shared__ unsigned short Xa[64][72];

    const int tid = threadIdx.x;
    const int lane = tid & 63;
    const int w = tid >> 6;
    const int lm = lane & 15;
    const int quad = lane >> 4;
    const int batch = blockIdx.x >> 5;
    const int c = blockIdx.x & 31;
    const size_t blk = (size_t)batch * 32 + c;

    float4v kk[4], qk[4];
#pragma unroll
    for (int i = 0; i < 4; ++i) { kk[i] = (float4v){0,0,0,0}; qk[i] = (float4v){0,0,0,0}; }

    const size_t tokA = (size_t)batch * 2048 + c * 64 + w * 16 + lm;
#pragma unroll 4
    for (int ks = 0; ks < 32; ++ks) {
        short8 aK = *(const short8*)(K + tokA * 1024 + ks * 32 + quad * 8);
        short8 aQ = *(const short8*)(Q + tokA * 1024 + ks * 32 + quad * 8);
#pragma unroll
        for (int nb = 0; nb < 4; ++nb) {
            size_t tokB = (size_t)batch * 2048 + c * 64 + nb * 16 + lm;
            short8 bK = *(const short8*)(K + tokB * 1024 + ks * 32 + quad * 8);
            kk[nb] = __builtin_amdgcn_mfma_f32_16x16x32_bf16(aK, bK, kk[nb], 0, 0, 0);
            qk[nb] = __builtin_amdgcn_mfma_f32_16x16x32_bf16(aQ, bK, qk[nb], 0, 0, 0);
        }
    }
#pragma unroll
    for (int nb = 0; nb < 4; ++nb)
#pragma unroll
        for (int r = 0; r < 4; ++r) {
            Skk[w * 16 + quad * 4 + r][nb * 16 + lm] = kk[nb][r];
            Sqk[w * 16 + quad * 4 + r][nb * 16 + lm] = qk[nb][r];
        }
    __syncthreads();

    const float c1 = 2.0f * LR / 1024.0f;
#pragma unroll
    for (int e = 0; e < 16; ++e) {
        int idx = tid * 16 + e;
        int t = idx >> 6, i = idx & 63;
        float a = (i < t) ? c1 * (Skk[t][i] + 1.0f) : 0.0f;
        Lb[t][i] = f2bf(a);
        Xa[i][t] = f2bf(((i == t) ? 1.0f : 0.0f) - a);
        float mq = (i <= t) ? -LR * (Sqk[t][i] + 1.0f) : 0.0f;
        MpG[blk * 4096 + (size_t)t * 64 + i] = f2bf(mq);
    }
    __syncthreads();

    short8 afL0 = *(const short8*)&Lb[w * 16 + lm][quad * 8];
    short8 afL1 = *(const short8*)&Lb[w * 16 + lm][32 + quad * 8];
    float4v p[4];
#pragma unroll
    for (int nb = 0; nb < 4; ++nb) {
        p[nb] = (float4v){0,0,0,0};
        short8 b0f = *(const short8*)&Xa[nb * 16 + lm][quad * 8];
        short8 b1f = *(const short8*)&Xa[nb * 16 + lm][32 + quad * 8];
        p[nb] = __builtin_amdgcn_mfma_f32_16x16x32_bf16(afL0, b0f, p[nb], 0, 0, 0);
        p[nb] = __builtin_amdgcn_mfma_f32_16x16x32_bf16(afL1, b1f, p[nb], 0, 0, 0);
    }
    __syncthreads();
#pragma unroll
    for (int nb = 0; nb < 4; ++nb)
#pragma unroll
        for (int r = 0; r < 4; ++r) {
            int ii = nb * 16 + lm, tt = w * 16 + quad * 4 + r;
            Xa[ii][tt] = f2bf(((ii == tt) ? 1.0f : 0.0f) - p[nb][r]);
        }
    __syncthreads();

#pragma unroll
    for (int nb = 0; nb < 4; ++nb) {
        p[nb] = (float4v){0,0,0,0};
        short8 b0f = *(const short8*)&Xa[nb * 16 + lm][quad * 8];
        short8 b1f = *(const short8*)&Xa[nb * 16 + lm][32 + quad * 8];
        p[nb] = __builtin_amdgcn_mfma_f32_16x16x32_bf16(afL0, b0f, p[nb], 0, 0, 0);
        p[nb] = __builtin_amdgcn_mfma_f32_16x16x32_bf16(afL1, b1f, p[nb], 0, 0, 0);
    }
#pragma unroll
    for (int nb = 0; nb < 4; ++nb)
#pragma unroll
        for (int r = 0; r < 4; ++r) {
            int ii = nb * 16 + lm, tt = w * 16 + quad * 4 + r;
            LinvG[blk * 4096 + (size_t)tt * 64 + ii] =
                f2bf(((ii == tt) ? 1.0f : 0.0f) - p[nb][r]);
        }
}

// ---------------------------------------------------------------------------
// Phase 3: chunked TTT, round-3 base + ROLE-SPLIT ONLY (bisection probe).
// 256 blocks = 8 batches x 32 row-slabs (32 rows), 512 threads (8 waves):
// wave = (token-group g = w&3, role = w>>2). Role 0: U = (2/d)(W K^T+b-V)
// for BOTH row halves (reads K only). Role 1: O = W Q^T for BOTH halves
// (reads Q only; accumulators stay in registers from (b) to (d)).
// Halves per-CU K/Q gather requests vs round 3. NO prefetch (round-4/6's
// other delta); Linv/Mp/Kt loaded inline exactly where round 3 loaded them.
// Barriers identical to round 3: B1 Wb, B2 Ut, B3 Gt, B4 end-of-chunk.
// ---------------------------------------------------------------------------
__global__ __launch_bounds__(512, 2) void ttt_chunk(
    const unsigned short* __restrict__ K,
    const unsigned short* __restrict__ V,
    const unsigned short* __restrict__ Q,
    const unsigned short* __restrict__ Kt,
    const unsigned short* __restrict__ Linv,
    const unsigned short* __restrict__ Mp,
    const float* __restrict__ W0,
    const float* __restrict__ b0,
    float* __restrict__ out)
{
    __shared__ unsigned short Wb[32][1032];   // bf16 W mirror (66 KB)
    __shared__ unsigned short Ut[32][72];
    __shared__ unsigned short Gt[32][72];
    __shared__ __align__(16) float bb[32];

    const int tid  = threadIdx.x;
    const int lane = tid & 63;
    const int w    = tid >> 6;          // wave 0..7
    const int g    = w & 3;             // token-group
    const int role = w >> 2;            // 0 = U-producer (K), 1 = O-producer (Q)
    const int lm   = lane & 15;
    const int quad = lane >> 4;
    const int batch = blockIdx.x & 7;
    const int r0    = (blockIdx.x >> 3) * 32;   // row-slab base (32 rows)

    // W init: wave w owns col-tiles nt = w + 8i (i<8), BOTH row halves.
    float4v acc_w[2][8];
#pragma unroll
    for (int rs2 = 0; rs2 < 2; ++rs2)
#pragma unroll
        for (int i = 0; i < 8; ++i) {
            int nt = w + 8 * i;
#pragma unroll
            for (int r = 0; r < 4; ++r)
                acc_w[rs2][i][r] =
                    W0[(size_t)(r0 + rs2 * 16 + quad * 4 + r) * 1024 + nt * 16 + lm];
        }
    if (tid < 32) bb[tid] = b0[r0 + tid];

    const size_t tokBase = (size_t)batch * 2048;
    const unsigned short* KtB = Kt + (size_t)batch * 2097152;
    const unsigned short* X = role ? Q : K;     // this wave's (b) operand stream
    const float sc = 2.0f / 1024.0f;

    for (int c = 0; c < 32; ++c) {
        // (a) dump fp32 W regs -> bf16 LDS mirror (both halves)  [= round 3]
#pragma unroll
        for (int rs2 = 0; rs2 < 2; ++rs2)
#pragma unroll
            for (int i = 0; i < 8; ++i) {
                int nt = w + 8 * i;
#pragma unroll
                for (int r = 0; r < 4; ++r)
                    Wb[rs2 * 16 + quad * 4 + r][nt * 16 + lm] = f2bf(acc_w[rs2][i][r]);
            }
        __syncthreads();   // B1: Wb ready

        // (b) role-split: full-k contraction of W (both row halves) against
        //     this wave's stream X (K for role 0 -> U; Q for role 1 -> O).
        //     Per-lane loads are verbatim round-3 expressions (rs=0/1 halves).
        const size_t tok = tokBase + c * 64 + g * 16 + lm;   // this lane's token
        const unsigned short* xRow  = X + tok * 1024 + quad * 8;
        const unsigned short* wRow0 = &Wb[lm][quad * 8];
        const unsigned short* wRow1 = &Wb[16 + lm][quad * 8];
        float4v a0v = (float4v){0,0,0,0};   // rows 0..15 accumulator
        float4v a1v = (float4v){0,0,0,0};   // rows 16..31 accumulator
#pragma unroll 8
        for (int ks = 0; ks < 32; ++ks) {
            short8 xf  = *(const short8*)(xRow + ks * 32);
            short8 af0 = *(const short8*)(wRow0 + ks * 32);
            short8 af1 = *(const short8*)(wRow1 + ks * 32);
            a0v = __builtin_amdgcn_mfma_f32_16x16x32_bf16(af0, xf, a0v, 0, 0, 0);
            a1v = __builtin_amdgcn_mfma_f32_16x16x32_bf16(af1, xf, a1v, 0, 0, 0);
        }
        float4v bval0 = *(const float4v*)&bb[quad * 4];
        float4v bval1 = *(const float4v*)&bb[16 + quad * 4];
        if (role == 0) {
            // U = (2/d)(W K^T + b - V): write Ut for both row halves
            ushort4v vv0 = *(const ushort4v*)(V + tok * 1024 + r0 + quad * 4);
            ushort4v vv1 = *(const ushort4v*)(V + tok * 1024 + r0 + 16 + quad * 4);
#pragma unroll
            for (int r = 0; r < 4; ++r) {
                Ut[quad * 4 + r][g * 16 + lm]      = f2bf(sc * (a0v[r] + bval0[r] - bf2f(vv0[r])));
                Ut[16 + quad * 4 + r][g * 16 + lm] = f2bf(sc * (a1v[r] + bval1[r] - bf2f(vv1[r])));
            }
        }
        __syncthreads();   // B2: Ut ready

        const size_t lbase = ((size_t)(batch * 32 + c)) * 4096 + (size_t)(g * 16 + lm) * 64;

        // (c) G^T: wave (g,role) handles row-half = role  [= round 3, rs=role]
        {
            float4v accG = (float4v){0,0,0,0};
            short8 a0 = *(const short8*)&Ut[role * 16 + lm][quad * 8];
            short8 a1 = *(const short8*)&Ut[role * 16 + lm][32 + quad * 8];
            short8 l0 = *(const short8*)(Linv + lbase + quad * 8);
            short8 l1 = *(const short8*)(Linv + lbase + 32 + quad * 8);
            accG = __builtin_amdgcn_mfma_f32_16x16x32_bf16(a0, l0, accG, 0, 0, 0);
            accG = __builtin_amdgcn_mfma_f32_16x16x32_bf16(a1, l1, accG, 0, 0, 0);
#pragma unroll
            for (int r = 0; r < 4; ++r)
                Gt[role * 16 + quad * 4 + r][g * 16 + lm] = f2bf(accG[r]);
        }
        __syncthreads();   // B3: Gt ready

        // shared Gt A-frags (rows lm and 16+lm) for (d) and (e)  [= round 3]
        short8 agA0 = *(const short8*)&Gt[lm][quad * 8];
        short8 agA1 = *(const short8*)&Gt[lm][32 + quad * 8];
        short8 agB0 = *(const short8*)&Gt[16 + lm][quad * 8];
        short8 agB1 = *(const short8*)&Gt[16 + lm][32 + quad * 8];

        // (d) role-1 waves: O += Gt . Mp + b ; store both row halves
        if (role == 1) {
            short8 m0f = *(const short8*)(Mp + lbase + quad * 8);
            short8 m1f = *(const short8*)(Mp + lbase + 32 + quad * 8);
            a0v = __builtin_amdgcn_mfma_f32_16x16x32_bf16(agA0, m0f, a0v, 0, 0, 0);
            a0v = __builtin_amdgcn_mfma_f32_16x16x32_bf16(agA1, m1f, a0v, 0, 0, 0);
            a1v = __builtin_amdgcn_mfma_f32_16x16x32_bf16(agB0, m0f, a1v, 0, 0, 0);
            a1v = __builtin_amdgcn_mfma_f32_16x16x32_bf16(agB1, m1f, a1v, 0, 0, 0);
            float4v ov0, ov1;
#pragma unroll
            for (int r = 0; r < 4; ++r) { ov0[r] = a0v[r] + bval0[r]; ov1[r] = a1v[r] + bval1[r]; }
            *(float4v*)(out + tok * 1024 + r0 + quad * 4)      = ov0;
            *(float4v*)(out + tok * 1024 + r0 + 16 + quad * 4) = ov1;
        }

        // (e) W += Gt . Kt-contraction, inline Kt loads  [= round 3]
#pragma unroll
        for (int i = 0; i < 8; ++i) {
            int nt = w + 8 * i;
            const unsigned short* kp = KtB + (size_t)(nt * 16 + lm) * 2048 + c * 64;
            short8 kb0 = *(const short8*)(kp + quad * 8);
            short8 kb1 = *(const short8*)(kp + 32 + quad * 8);
            acc_w[0][i] = __builtin_amdgcn_mfma_f32_16x16x32_bf16(agA0, kb0, acc_w[0][i], 0, 0, 0);
            acc_w[0][i] = __builtin_amdgcn_mfma_f32_16x16x32_bf16(agA1, kb1, acc_w[0][i], 0, 0, 0);
            acc_w[1][i] = __builtin_amdgcn_mfma_f32_16x16x32_bf16(agB0, kb0, acc_w[1][i], 0, 0, 0);
            acc_w[1][i] = __builtin_amdgcn_mfma_f32_16x16x32_bf16(agB1, kb1, acc_w[1][i], 0, 0, 0);
        }

        // (f) bias update: wave 0, 2 lanes per row + shuffle reduce  [= round 3]
        if (w == 0) {
            int row = lane >> 1, part = lane & 1;
            float s = 0.f;
#pragma unroll
            for (int t = 0; t < 32; ++t) s += bf2f(Gt[row][part * 32 + t]);
            s += __shfl_xor(s, 1);
            if (part == 0) bb[row] -= LR * s;
        }
        __syncthreads();   // B4: end-of-chunk (bb/Gt/Wb safe for next chunk)
    }
}

// ---------------------------------------------------------------------------
extern "C" void kernel_launch(void* const* d_in, const int* in_sizes, int n_in,
                              void* d_out, int out_size, void* d_ws, size_t ws_size,
                              hipStream_t stream) {
    (void)in_sizes; (void)n_in; (void)out_size; (void)ws_size;
    const float* in_seq = (const float*)d_in[0];
    const float* thK    = (const float*)d_in[1];
    const float* thV    = (const float*)d_in[2];
    const float* thQ    = (const float*)d_in[3];
    const float* W0     = (const float*)d_in[4];
    const float* b0     = (const float*)d_in[5];
    float* out = (float*)d_out;

    unsigned short* ws = (unsigned short*)d_ws;
    unsigned short* Kp   = ws;                                  // 32 MB
    unsigned short* Vp   = ws + (size_t)16384 * 1024;           // 32 MB
    unsigned short* Qp   = ws + (size_t)2 * 16384 * 1024;       // 32 MB
    unsigned short* Ktp  = ws + (size_t)3 * 16384 * 1024;       // 32 MB
    unsigned short* Linv = ws + (size_t)4 * 16384 * 1024;       // 2 MB
    unsigned short* Mpp  = Linv + (size_t)8 * 32 * 4096;        // 2 MB

    dim3 g1(16384 / 64, 1024 / 64);
    proj_gemm<<<g1, 256, 0, stream>>>(in_seq, thK, thV, thQ, Kp, Ktp);

    precomp<<<256, 256, 0, stream>>>(Kp, Qp, Linv, Mpp);

    ttt_chunk<<<256, 512, 0, stream>>>(Kp, Vp, Qp, Ktp, Linv, Mpp, W0, b0, out);
}

// Round 8
// 766.745 us; speedup vs baseline: 1.6332x; 1.0691x over previous
//
#include <hip/hip_runtime.h>
#include <hip/hip_bf16.h>

#define LR 0.01f

typedef __attribute__((ext_vector_type(8))) short short8;
typedef __attribute__((ext_vector_type(4))) float float4v;
typedef __attribute__((ext_vector_type(4))) unsigned short ushort4v;

static __device__ __forceinline__ unsigned short f2bf(float x) {
    union { float f; unsigned u; } un; un.f = x;
    unsigned r = un.u + 0x7fffu + ((un.u >> 16) & 1u);   // RNE
    return (unsigned short)(r >> 16);
}
static __device__ __forceinline__ float bf2f(unsigned short x) {
    union { float f; unsigned u; } un; un.u = ((unsigned)x) << 16;
    return un.f;
}

// ---------------------------------------------------------------------------
// Phase 0 (new): one-shot fp32 -> bf16 cast of A (16384x1024) and the three
// theta matrices (1024x1024 each) into workspace. Same RNE rounding as the
// in-kernel f2bf -> downstream results bit-identical to the verified path.
// Blocks 0..2047: A (grid-stride). Blocks 2048..2431: 128 blocks per theta.
// ---------------------------------------------------------------------------
__global__ __launch_bounds__(256) void cast_all(
    const float* __restrict__ A,
    const float* __restrict__ T0, const float* __restrict__ T1,
    const float* __restrict__ T2,
    unsigned short* __restrict__ Ab,
    unsigned short* __restrict__ Tb)
{
    const int bid = blockIdx.x;
    const int tid = threadIdx.x;
    if (bid < 2048) {
        // A: 2,097,152 groups of 8 floats
        for (int i = bid * 256 + tid; i < 2097152; i += 2048 * 256) {
            const float4v* s = (const float4v*)(A + (size_t)i * 8);
            float4v a = s[0], b = s[1];
            short8 o;
#pragma unroll
            for (int j = 0; j < 4; ++j) { o[j] = (short)f2bf(a[j]); o[j + 4] = (short)f2bf(b[j]); }
            *(short8*)(Ab + (size_t)i * 8) = o;
        }
    } else {
        const int base = bid - 2048;
        const int t = base >> 7;           // theta index 0..2
        const int lb = base & 127;         // local block 0..127
        const float* S = (t == 0) ? T0 : (t == 1 ? T1 : T2);
        unsigned short* D = Tb + (size_t)t * 1048576;
        // each theta: 131,072 groups of 8 floats
        for (int i = lb * 256 + tid; i < 131072; i += 128 * 256) {
            const float4v* s = (const float4v*)(S + (size_t)i * 8);
            float4v a = s[0], b = s[1];
            short8 o;
#pragma unroll
            for (int j = 0; j < 4; ++j) { o[j] = (short)f2bf(a[j]); o[j + 4] = (short)f2bf(b[j]); }
            *(short8*)(D + (size_t)i * 8) = o;
        }
    }
}

// ---------------------------------------------------------------------------
// Phase 1 (new fast path): K/V/Q projections from PRE-CAST bf16 A/thetas.
// Identical structure to the round-3-verified z-merged proj_gemm; staging
// bytes halved (16B/lane short8 loads), no per-tile f2bf on inputs.
// Also writes Kt = -LR * K^T  [b][j][s].
// ---------------------------------------------------------------------------
__global__ __launch_bounds__(256) void proj_gemm_bf(
    const unsigned short* __restrict__ A,    // bf16 [16384][1024]
    const unsigned short* __restrict__ Tb,   // bf16 [3][1024][1024]
    unsigned short* __restrict__ out,
    unsigned short* __restrict__ ktw)
{
    __shared__ unsigned short As[64][40];
    __shared__ unsigned short Bs[3][64][40];

    const int tid  = threadIdx.x;
    const int lane = tid & 63;
    const int wave = tid >> 6;
    const int m0 = blockIdx.x * 64;
    const int n0 = blockIdx.y * 64;
    const int srow = tid >> 2;
    const int sseg = (tid & 3) * 8;
    const int mrow = lane & 15;
    const int quad = lane >> 4;

    float4v acc[3][4];
#pragma unroll
    for (int z = 0; z < 3; ++z)
#pragma unroll
        for (int i = 0; i < 4; ++i) acc[z][i] = (float4v){0.f, 0.f, 0.f, 0.f};

    const unsigned short* apBase = A  + (size_t)(m0 + srow) * 1024 + sseg;
    const unsigned short* bp0 = Tb               + (size_t)(n0 + srow) * 1024 + sseg;
    const unsigned short* bp1 = Tb + 1048576     + (size_t)(n0 + srow) * 1024 + sseg;
    const unsigned short* bp2 = Tb + 2 * 1048576 + (size_t)(n0 + srow) * 1024 + sseg;

    for (int kt = 0; kt < 1024; kt += 32) {
        short8 av = *(const short8*)(apBase + kt);
        short8 b0 = *(const short8*)(bp0 + kt);
        short8 b1 = *(const short8*)(bp1 + kt);
        short8 b2 = *(const short8*)(bp2 + kt);

        __syncthreads();
        *(short8*)&As[srow][sseg]    = av;
        *(short8*)&Bs[0][srow][sseg] = b0;
        *(short8*)&Bs[1][srow][sseg] = b1;
        *(short8*)&Bs[2][srow][sseg] = b2;
        __syncthreads();

        short8 af = *(const short8*)&As[16 * wave + mrow][quad * 8];
#pragma unroll
        for (int z = 0; z < 3; ++z)
#pragma unroll
            for (int nb = 0; nb < 4; ++nb) {
                short8 bfr = *(const short8*)&Bs[z][16 * nb + mrow][quad * 8];
                acc[z][nb] = __builtin_amdgcn_mfma_f32_16x16x32_bf16(af, bfr, acc[z][nb], 0, 0, 0);
            }
    }

    const int batch = m0 >> 11;
    const int s0    = m0 & 2047;
#pragma unroll
    for (int z = 0; z < 3; ++z) {
        unsigned short* C = out + (size_t)z * (size_t)16384 * 1024;
#pragma unroll
        for (int nb = 0; nb < 4; ++nb) {
#pragma unroll
            for (int r = 0; r < 4; ++r) {
                int tl = 16 * wave + quad * 4 + r;     // token-local
                int jl = 16 * nb + mrow;               // dim-local
                C[(size_t)(m0 + tl) * 1024 + (n0 + jl)] = f2bf(acc[z][nb][r]);
                if (z == 0) {
                    ktw[(size_t)batch * 2097152 + (size_t)(n0 + jl) * 2048 + s0 + tl] =
                        f2bf(-LR * acc[0][nb][r]);
                }
            }
        }
    }
}

// ---------------------------------------------------------------------------
// Phase 1 (fallback, verified round 3): fp32-input z-merged proj. Used only
// if the workspace is too small for the pre-cast buffers.
// ---------------------------------------------------------------------------
__global__ __launch_bounds__(256) void proj_gemm(
    const float* __restrict__ A,
    const float* __restrict__ T0, const float* __restrict__ T1,
    const float* __restrict__ T2,
    unsigned short* __restrict__ out,
    unsigned short* __restrict__ ktw)
{
    __shared__ unsigned short As[64][40];
    __shared__ unsigned short Bs[3][64][40];

    const int tid  = threadIdx.x;
    const int lane = tid & 63;
    const int wave = tid >> 6;
    const int m0 = blockIdx.x * 64;
    const int n0 = blockIdx.y * 64;
    const int srow = tid >> 2;
    const int sseg = (tid & 3) * 8;
    const int mrow = lane & 15;
    const int quad = lane >> 4;

    float4v acc[3][4];
#pragma unroll
    for (int z = 0; z < 3; ++z)
#pragma unroll
        for (int i = 0; i < 4; ++i) acc[z][i] = (float4v){0.f, 0.f, 0.f, 0.f};

    const float* apBase = A  + (size_t)(m0 + srow) * 1024 + sseg;
    const float* bp0 = T0 + (size_t)(n0 + srow) * 1024 + sseg;
    const float* bp1 = T1 + (size_t)(n0 + srow) * 1024 + sseg;
    const float* bp2 = T2 + (size_t)(n0 + srow) * 1024 + sseg;

    for (int kt = 0; kt < 1024; kt += 32) {
        float4v av0 = ((const float4v*)(apBase + kt))[0];
        float4v av1 = ((const float4v*)(apBase + kt))[1];
        float4v b00 = ((const float4v*)(bp0 + kt))[0], b01 = ((const float4v*)(bp0 + kt))[1];
        float4v b10 = ((const float4v*)(bp1 + kt))[0], b11 = ((const float4v*)(bp1 + kt))[1];
        float4v b20 = ((const float4v*)(bp2 + kt))[0], b21 = ((const float4v*)(bp2 + kt))[1];

        __syncthreads();
        short8 apk, bpk0, bpk1, bpk2;
#pragma unroll
        for (int i = 0; i < 4; ++i) {
            apk[i]      = (short)f2bf(av0[i]);
            apk[i + 4]  = (short)f2bf(av1[i]);
            bpk0[i]     = (short)f2bf(b00[i]);
            bpk0[i + 4] = (short)f2bf(b01[i]);
            bpk1[i]     = (short)f2bf(b10[i]);
            bpk1[i + 4] = (short)f2bf(b11[i]);
            bpk2[i]     = (short)f2bf(b20[i]);
            bpk2[i + 4] = (short)f2bf(b21[i]);
        }
        *(short8*)&As[srow][sseg]    = apk;
        *(short8*)&Bs[0][srow][sseg] = bpk0;
        *(short8*)&Bs[1][srow][sseg] = bpk1;
        *(short8*)&Bs[2][srow][sseg] = bpk2;
        __syncthreads();

        short8 af = *(const short8*)&As[16 * wave + mrow][quad * 8];
#pragma unroll
        for (int z = 0; z < 3; ++z)
#pragma unroll
            for (int nb = 0; nb < 4; ++nb) {
                short8 bfr = *(const short8*)&Bs[z][16 * nb + mrow][quad * 8];
                acc[z][nb] = __builtin_amdgcn_mfma_f32_16x16x32_bf16(af, bfr, acc[z][nb], 0, 0, 0);
            }
    }

    const int batch = m0 >> 11;
    const int s0    = m0 & 2047;
#pragma unroll
    for (int z = 0; z < 3; ++z) {
        unsigned short* C = out + (size_t)z * (size_t)16384 * 1024;
#pragma unroll
        for (int nb = 0; nb < 4; ++nb) {
#pragma unroll
            for (int r = 0; r < 4; ++r) {
                int tl = 16 * wave + quad * 4 + r;     // token-local
                int jl = 16 * nb + mrow;               // dim-local
                C[(size_t)(m0 + tl) * 1024 + (n0 + jl)] = f2bf(acc[z][nb][r]);
                if (z == 0) {
                    ktw[(size_t)batch * 2097152 + (size_t)(n0 + jl) * 2048 + s0 + tl] =
                        f2bf(-LR * acc[0][nb][r]);
                }
            }
        }
    }
}

// ---------------------------------------------------------------------------
// Phase 2: per (batch, chunk): Linv = (I+L)^-1 via Neumann (I - L + L^2 - L^3),
// Mp = -LR * tril(Q K^T + 1). L = (2LR/d)*strict_tril(K K^T + 1).  (unchanged)
// ---------------------------------------------------------------------------
__global__ __launch_bounds__(256) void precomp(
    const unsigned short* __restrict__ K,
    const unsigned short* __restrict__ Q,
    unsigned short* __restrict__ LinvG,
    unsigned short* __restrict__ MpG)
{
    __shared__ float Skk[64][68];
    __shared__ float Sqk[64][68];
    __shared__ unsigned short Lb[64][72];
    __shared__ unsigned short Xa[64][72];

    const int tid = threadIdx.x;
    const int lane = tid & 63;
    const int w = tid >> 6;
    const int lm = lane & 15;
    const int quad = lane >> 4;
    const int batch = blockIdx.x >> 5;
    const int c = blockIdx.x & 31;
    const size_t blk = (size_t)batch * 32 + c;

    float4v kk[4], qk[4];
#pragma unroll
    for (int i = 0; i < 4; ++i) { kk[i] = (float4v){0,0,0,0}; qk[i] = (float4v){0,0,0,0}; }

    const size_t tokA = (size_t)batch * 2048 + c * 64 + w * 16 + lm;
#pragma unroll 4
    for (int ks = 0; ks < 32; ++ks) {
        short8 aK = *(const short8*)(K + tokA * 1024 + ks * 32 + quad * 8);
        short8 aQ = *(const short8*)(Q + tokA * 1024 + ks * 32 + quad * 8);
#pragma unroll
        for (int nb = 0; nb < 4; ++nb) {
            size_t tokB = (size_t)batch * 2048 + c * 64 + nb * 16 + lm;
            short8 bK = *(const short8*)(K + tokB * 1024 + ks * 32 + quad * 8);
            kk[nb] = __builtin_amdgcn_mfma_f32_16x16x32_bf16(aK, bK, kk[nb], 0, 0, 0);
            qk[nb] = __builtin_amdgcn_mfma_f32_16x16x32_bf16(aQ, bK, qk[nb], 0, 0, 0);
        }
    }
#pragma unroll
    for (int nb = 0; nb < 4; ++nb)
#pragma unroll
        for (int r = 0; r < 4; ++r) {
            Skk[w * 16 + quad * 4 + r][nb * 16 + lm] = kk[nb][r];
            Sqk[w * 16 + quad * 4 + r][nb * 16 + lm] = qk[nb][r];
        }
    __syncthreads();

    const float c1 = 2.0f * LR / 1024.0f;
#pragma unroll
    for (int e = 0; e < 16; ++e) {
        int idx = tid * 16 + e;
        int t = idx >> 6, i = idx & 63;
        float a = (i < t) ? c1 * (Skk[t][i] + 1.0f) : 0.0f;
        Lb[t][i] = f2bf(a);
        Xa[i][t] = f2bf(((i == t) ? 1.0f : 0.0f) - a);
        float mq = (i <= t) ? -LR * (Sqk[t][i] + 1.0f) : 0.0f;
        MpG[blk * 4096 + (size_t)t * 64 + i] = f2bf(mq);
    }
    __syncthreads();

    short8 afL0 = *(const short8*)&Lb[w * 16 + lm][quad * 8];
    short8 afL1 = *(const short8*)&Lb[w * 16 + lm][32 + quad * 8];
    float4v p[4];
#pragma unroll
    for (int nb = 0; nb < 4; ++nb) {
        p[nb] = (float4v){0,0,0,0};
        short8 b0f = *(const short8*)&Xa[nb * 16 + lm][quad * 8];
        short8 b1f = *(const short8*)&Xa[nb * 16 + lm][32 + quad * 8];
        p[nb] = __builtin_amdgcn_mfma_f32_16x16x32_bf16(afL0, b0f, p[nb], 0, 0, 0);
        p[nb] = __builtin_amdgcn_mfma_f32_16x16x32_bf16(afL1, b1f, p[nb], 0, 0, 0);
    }
    __syncthreads();
#pragma unroll
    for (int nb = 0; nb < 4; ++nb)
#pragma unroll
        for (int r = 0; r < 4; ++r) {
            int ii = nb * 16 + lm, tt = w * 16 + quad * 4 + r;
            Xa[ii][tt] = f2bf(((ii == tt) ? 1.0f : 0.0f) - p[nb][r]);
        }
    __syncthreads();

#pragma unroll
    for (int nb = 0; nb < 4; ++nb) {
        p[nb] = (float4v){0,0,0,0};
        short8 b0f = *(const short8*)&Xa[nb * 16 + lm][quad * 8];
        short8 b1f = *(const short8*)&Xa[nb * 16 + lm][32 + quad * 8];
        p[nb] = __builtin_amdgcn_mfma_f32_16x16x32_bf16(afL0, b0f, p[nb], 0, 0, 0);
        p[nb] = __builtin_amdgcn_mfma_f32_16x16x32_bf16(afL1, b1f, p[nb], 0, 0, 0);
    }
#pragma unroll
    for (int nb = 0; nb < 4; ++nb)
#pragma unroll
        for (int r = 0; r < 4; ++r) {
            int ii = nb * 16 + lm, tt = w * 16 + quad * 4 + r;
            LinvG[blk * 4096 + (size_t)tt * 64 + ii] =
                f2bf(((ii == tt) ? 1.0f : 0.0f) - p[nb][r]);
        }
}

// ---------------------------------------------------------------------------
// Phase 3: chunked TTT with role-split (VERIFIED round 7 — byte-identical).
// 256 blocks = 8 batches x 32 row-slabs (32 rows), 512 threads (8 waves):
// wave = (token-group g = w&3, role = w>>2). Role 0: U (reads K only).
// Role 1: O (reads Q only; accumulators in registers from (b) to (d)).
// ---------------------------------------------------------------------------
__global__ __launch_bounds__(512, 2) void ttt_chunk(
    const unsigned short* __restrict__ K,
    const unsigned short* __restrict__ V,
    const unsigned short* __restrict__ Q,
    const unsigned short* __restrict__ Kt,
    const unsigned short* __restrict__ Linv,
    const unsigned short* __restrict__ Mp,
    const float* __restrict__ W0,
    const float* __restrict__ b0,
    float* __restrict__ out)
{
    __shared__ unsigned short Wb[32][1032];   // bf16 W mirror (66 KB)
    __shared__ unsigned short Ut[32][72];
    __shared__ unsigned short Gt[32][72];
    __shared__ __align__(16) float bb[32];

    const int tid  = threadIdx.x;
    const int lane = tid & 63;
    const int w    = tid >> 6;          // wave 0..7
    const int g    = w & 3;             // token-group
    const int role = w >> 2;            // 0 = U-producer (K), 1 = O-producer (Q)
    const int lm   = lane & 15;
    const int quad = lane >> 4;
    const int batch = blockIdx.x & 7;
    const int r0    = (blockIdx.x >> 3) * 32;   // row-slab base (32 rows)

    // W init: wave w owns col-tiles nt = w + 8i (i<8), BOTH row halves.
    float4v acc_w[2][8];
#pragma unroll
    for (int rs2 = 0; rs2 < 2; ++rs2)
#pragma unroll
        for (int i = 0; i < 8; ++i) {
            int nt = w + 8 * i;
#pragma unroll
            for (int r = 0; r < 4; ++r)
                acc_w[rs2][i][r] =
                    W0[(size_t)(r0 + rs2 * 16 + quad * 4 + r) * 1024 + nt * 16 + lm];
        }
    if (tid < 32) bb[tid] = b0[r0 + tid];

    const size_t tokBase = (size_t)batch * 2048;
    const unsigned short* KtB = Kt + (size_t)batch * 2097152;
    const unsigned short* X = role ? Q : K;     // this wave's (b) operand stream
    const float sc = 2.0f / 1024.0f;

    for (int c = 0; c < 32; ++c) {
        // (a) dump fp32 W regs -> bf16 LDS mirror (both halves)
#pragma unroll
        for (int rs2 = 0; rs2 < 2; ++rs2)
#pragma unroll
            for (int i = 0; i < 8; ++i) {
                int nt = w + 8 * i;
#pragma unroll
                for (int r = 0; r < 4; ++r)
                    Wb[rs2 * 16 + quad * 4 + r][nt * 16 + lm] = f2bf(acc_w[rs2][i][r]);
            }
        __syncthreads();   // B1: Wb ready

        // (b) role-split: full-k contraction of W (both row halves) against
        //     this wave's stream X (K for role 0 -> U; Q for role 1 -> O).
        const size_t tok = tokBase + c * 64 + g * 16 + lm;   // this lane's token
        const unsigned short* xRow  = X + tok * 1024 + quad * 8;
        const unsigned short* wRow0 = &Wb[lm][quad * 8];
        const unsigned short* wRow1 = &Wb[16 + lm][quad * 8];
        float4v a0v = (float4v){0,0,0,0};   // rows 0..15 accumulator
        float4v a1v = (float4v){0,0,0,0};   // rows 16..31 accumulator
#pragma unroll 8
        for (int ks = 0; ks < 32; ++ks) {
            short8 xf  = *(const short8*)(xRow + ks * 32);
            short8 af0 = *(const short8*)(wRow0 + ks * 32);
            short8 af1 = *(const short8*)(wRow1 + ks * 32);
            a0v = __builtin_amdgcn_mfma_f32_16x16x32_bf16(af0, xf, a0v, 0, 0, 0);
            a1v = __builtin_amdgcn_mfma_f32_16x16x32_bf16(af1, xf, a1v, 0, 0, 0);
        }
        float4v bval0 = *(const float4v*)&bb[quad * 4];
        float4v bval1 = *(const float4v*)&bb[16 + quad * 4];
        if (role == 0) {
            // U = (2/d)(W K^T + b - V): write Ut for both row halves
            ushort4v vv0 = *(const ushort4v*)(V + tok * 1024 + r0 + quad * 4);
            ushort4v vv1 = *(const ushort4v*)(V + tok * 1024 + r0 + 16 + quad * 4);
#pragma unroll
            for (int r = 0; r < 4; ++r) {
                Ut[quad * 4 + r][g * 16 + lm]      = f2bf(sc * (a0v[r] + bval0[r] - bf2f(vv0[r])));
                Ut[16 + quad * 4 + r][g * 16 + lm] = f2bf(sc * (a1v[r] + bval1[r] - bf2f(vv1[r])));
            }
        }
        __syncthreads();   // B2: Ut ready

        const size_t lbase = ((size_t)(batch * 32 + c)) * 4096 + (size_t)(g * 16 + lm) * 64;

        // (c) G^T: wave (g,role) handles row-half = role
        {
            float4v accG = (float4v){0,0,0,0};
            short8 a0 = *(const short8*)&Ut[role * 16 + lm][quad * 8];
            short8 a1 = *(const short8*)&Ut[role * 16 + lm][32 + quad * 8];
            short8 l0 = *(const short8*)(Linv + lbase + quad * 8);
            short8 l1 = *(const short8*)(Linv + lbase + 32 + quad * 8);
            accG = __builtin_amdgcn_mfma_f32_16x16x32_bf16(a0, l0, accG, 0, 0, 0);
            accG = __builtin_amdgcn_mfma_f32_16x16x32_bf16(a1, l1, accG, 0, 0, 0);
#pragma unroll
            for (int r = 0; r < 4; ++r)
                Gt[role * 16 + quad * 4 + r][g * 16 + lm] = f2bf(accG[r]);
        }
        __syncthreads();   // B3: Gt ready

        // shared Gt A-frags (rows lm and 16+lm) for (d) and (e)
        short8 agA0 = *(const short8*)&Gt[lm][quad * 8];
        short8 agA1 = *(const short8*)&Gt[lm][32 + quad * 8];
        short8 agB0 = *(const short8*)&Gt[16 + lm][quad * 8];
        short8 agB1 = *(const short8*)&Gt[16 + lm][32 + quad * 8];

        // (d) role-1 waves: O += Gt . Mp + b ; store both row halves
        if (role == 1) {
            short8 m0f = *(const short8*)(Mp + lbase + quad * 8);
            short8 m1f = *(const short8*)(Mp + lbase + 32 + quad * 8);
            a0v = __builtin_amdgcn_mfma_f32_16x16x32_bf16(agA0, m0f, a0v, 0, 0, 0);
            a0v = __builtin_amdgcn_mfma_f32_16x16x32_bf16(agA1, m1f, a0v, 0, 0, 0);
            a1v = __builtin_amdgcn_mfma_f32_16x16x32_bf16(agB0, m0f, a1v, 0, 0, 0);
            a1v = __builtin_amdgcn_mfma_f32_16x16x32_bf16(agB1, m1f, a1v, 0, 0, 0);
            float4v ov0, ov1;
#pragma unroll
            for (int r = 0; r < 4; ++r) { ov0[r] = a0v[r] + bval0[r]; ov1[r] = a1v[r] + bval1[r]; }
            *(float4v*)(out + tok * 1024 + r0 + quad * 4)      = ov0;
            *(float4v*)(out + tok * 1024 + r0 + 16 + quad * 4) = ov1;
        }

        // (e) W += Gt . Kt-contraction, inline Kt loads
#pragma unroll
        for (int i = 0; i < 8; ++i) {
            int nt = w + 8 * i;
            const unsigned short* kp = KtB + (size_t)(nt * 16 + lm) * 2048 + c * 64;
            short8 kb0 = *(const short8*)(kp + quad * 8);
            short8 kb1 = *(const short8*)(kp + 32 + quad * 8);
            acc_w[0][i] = __builtin_amdgcn_mfma_f32_16x16x32_bf16(agA0, kb0, acc_w[0][i], 0, 0, 0);
            acc_w[0][i] = __builtin_amdgcn_mfma_f32_16x16x32_bf16(agA1, kb1, acc_w[0][i], 0, 0, 0);
            acc_w[1][i] = __builtin_amdgcn_mfma_f32_16x16x32_bf16(agB0, kb0, acc_w[1][i], 0, 0, 0);
            acc_w[1][i] = __builtin_amdgcn_mfma_f32_16x16x32_bf16(agB1, kb1, acc_w[1][i], 0, 0, 0);
        }

        // (f) bias update: wave 0, 2 lanes per row + shuffle reduce
        if (w == 0) {
            int row = lane >> 1, part = lane & 1;
            float s = 0.f;
#pragma unroll
            for (int t = 0; t < 32; ++t) s += bf2f(Gt[row][part * 32 + t]);
            s += __shfl_xor(s, 1);
            if (part == 0) bb[row] -= LR * s;
        }
        __syncthreads();   // B4: end-of-chunk (bb/Gt/Wb safe for next chunk)
    }
}

// ---------------------------------------------------------------------------
extern "C" void kernel_launch(void* const* d_in, const int* in_sizes, int n_in,
                              void* d_out, int out_size, void* d_ws, size_t ws_size,
                              hipStream_t stream) {
    (void)in_sizes; (void)n_in; (void)out_size;
    const float* in_seq = (const float*)d_in[0];
    const float* thK    = (const float*)d_in[1];
    const float* thV    = (const float*)d_in[2];
    const float* thQ    = (const float*)d_in[3];
    const float* W0     = (const float*)d_in[4];
    const float* b0     = (const float*)d_in[5];
    float* out = (float*)d_out;

    unsigned short* ws = (unsigned short*)d_ws;
    unsigned short* Kp   = ws;                                  // 32 MB
    unsigned short* Vp   = ws + (size_t)16384 * 1024;           // 32 MB
    unsigned short* Qp   = ws + (size_t)2 * 16384 * 1024;       // 32 MB
    unsigned short* Ktp  = ws + (size_t)3 * 16384 * 1024;       // 32 MB
    unsigned short* Linv = ws + (size_t)4 * 16384 * 1024;       // 2 MB
    unsigned short* Mpp  = Linv + (size_t)8 * 32 * 4096;        // 2 MB
    unsigned short* Abf  = Mpp + (size_t)8 * 32 * 4096;         // 32 MB (pre-cast A)
    unsigned short* Tbf  = Abf + (size_t)16384 * 1024;          // 6 MB  (pre-cast thetas)

    // shorts needed through Tbf end:
    const size_t need_shorts = (size_t)4 * 16384 * 1024 + 2 * (size_t)8 * 32 * 4096
                             + (size_t)16384 * 1024 + (size_t)3 * 1024 * 1024;

    dim3 g1(16384 / 64, 1024 / 64);
    if (ws_size >= need_shorts * 2) {
        cast_all<<<2432, 256, 0, stream>>>(in_seq, thK, thV, thQ, Abf, Tbf);
        proj_gemm_bf<<<g1, 256, 0, stream>>>(Abf, Tbf, Kp, Ktp);
    } else {
        proj_gemm<<<g1, 256, 0, stream>>>(in_seq, thK, thV, thQ, Kp, Ktp);
    }

    precomp<<<256, 256, 0, stream>>>(Kp, Qp, Linv, Mpp);

    ttt_chunk<<<256, 512, 0, stream>>>(Kp, Vp, Qp, Ktp, Linv, Mpp, W0, b0, out);
}